// Round 1
// 1868.210 us; speedup vs baseline: 1.0160x; 1.0160x over previous
//
#include <hip/hip_runtime.h>

// LayerNorm-LSTM: B=16384, T=16, I=256, H=128, G=4H=512.
// Round 3 restructure:
//  - Hoist phase A (x @ W_ih^T + LN_x*gx + all biases) out of the serial
//    16-step chain into one massively-parallel GEMM over all B*T rows,
//    materializing A[B][T][G] fp32 in ws (536 MB; ws is 1 GiB per the
//    observed harness fill). fp32 store is bit-identical to the previous
//    in-register values -> absmax unchanged.
//  - The recurrence is batch-row independent -> ONE persistent kernel:
//    each block owns 32 batch rows for all 16 steps. h lives in LDS as
//    split-bf16 (XOR-swizzled so MFMA-fragment ds_read_b128 is 2-way =
//    free), c lives in registers, A_t is prefetched into registers during
//    the previous step's phase 2 (its live range avoids phase B's peak).
//  - Eliminates: 16 launches, per-step h/c global round-trips (33.6 MB/step),
//    per-step W_ih refetch, per-step x split VALU.

#define B_  16384
#define T_  16
#define I_  256
#define H_  128
#define G_  512
#define EPS 1e-5f

typedef __attribute__((ext_vector_type(8))) short short8;   // 8 bf16 in 4 VGPRs
typedef __attribute__((ext_vector_type(4))) float f32x4;    // MFMA C/D frag

__device__ __forceinline__ unsigned short f2bf(float f) {
    union { float f; unsigned u; } v; v.f = f;
    unsigned u = v.u;
    return (unsigned short)((u + 0x7FFFu + ((u >> 16) & 1u)) >> 16); // RNE
}
__device__ __forceinline__ float bf2f(unsigned short b) {
    union { unsigned u; float f; } v; v.u = ((unsigned)b) << 16;
    return v.f;
}
// split f32 -> hi (RTZ bf16) + lo (bf16 of exact residual)
__device__ __forceinline__ void split_bf(float x, unsigned short& hi, unsigned short& lo) {
    union { float f; unsigned u; } v; v.f = x;
    hi = (unsigned short)(v.u >> 16);
    lo = f2bf(x - bf2f(hi));
}

__device__ __forceinline__ float sigm_(float x) { return 1.0f / (1.0f + __expf(-x)); }
__device__ __forceinline__ float tanh_(float x) { return 1.0f - 2.0f / (__expf(2.0f * x) + 1.0f); }

// LDS gate buffer index with quad-XOR swizzle (2-way bank aliasing max = free).
#define GIDX(g, row, col) ((((g) * 32 + (row)) * 128) + ((col) ^ (((row) & 12) << 2)))
// LDS h buffer index: XOR k-bits 3..5 by row so phase-B ds_read_b128 of the
// MFMA A-fragment (16 rows x 8 consecutive k) is 2-way bank aliased (free).
#define HIDX(row, k) (((row) << 7) + ((k) ^ (((row) & 7) << 3)))

__global__ void prep_kernel(const float* __restrict__ Wih, const float* __restrict__ Whh,
                            unsigned short* __restrict__ wih_hi, unsigned short* __restrict__ wih_lo,
                            unsigned short* __restrict__ whh_hi, unsigned short* __restrict__ whh_lo) {
    const int NW_IH = G_ * I_;          // 131072
    const int NW_HH = G_ * H_;          // 65536
    int stride = gridDim.x * blockDim.x;
    for (int i = blockIdx.x * blockDim.x + threadIdx.x; i < NW_IH + NW_HH; i += stride) {
        unsigned short hi, lo;
        if (i < NW_IH) { split_bf(Wih[i], hi, lo); wih_hi[i] = hi; wih_lo[i] = lo; }
        else { int j = i - NW_IH; split_bf(Whh[j], hi, lo); whh_hi[j] = hi; whh_lo[j] = lo; }
    }
}

// ---- xproj: A[n][g] = LN_x(x_n @ Wih^T) * gx + (bx + bh + b), n = b*T+t ----
__launch_bounds__(256, 2)
__global__ void xproj_kernel(const float* __restrict__ x,                 // [B*T, I] fp32
                             const unsigned short* __restrict__ wih_hi,   // [G,I]
                             const unsigned short* __restrict__ wih_lo,   // [G,I]
                             const float* __restrict__ gx, const float* __restrict__ bx,
                             const float* __restrict__ bh, const float* __restrict__ bias,
                             float* __restrict__ A) {                     // [B*T, G] fp32
    const int tid  = threadIdx.x;
    const int w    = tid >> 6;     // wave id == gate chunk id
    const int lane = tid & 63;
    const int l15  = lane & 15;
    const int quad = lane >> 4;
    const int n0   = blockIdx.x * 32;

    float gx_c[8], bs_c[8];
#pragma unroll
    for (int c = 0; c < 8; ++c) {
        int col = w * 128 + c * 16 + l15;
        gx_c[c] = gx[col];
        bs_c[c] = bx[col] + bh[col] + bias[col];
    }

    f32x4 acc[2][8];
#pragma unroll
    for (int r = 0; r < 2; ++r)
#pragma unroll
        for (int c = 0; c < 8; ++c) acc[r][c] = (f32x4){0.f, 0.f, 0.f, 0.f};

    for (int kk = 0; kk < 8; ++kk) {
        int k0 = kk * 32 + quad * 8;
        short8 ahi[2], alo[2];
#pragma unroll
        for (int r = 0; r < 2; ++r) {
            const float* xp = x + (size_t)(n0 + r * 16 + l15) * I_ + k0;
            float4 v0 = *(const float4*)xp;
            float4 v1 = *(const float4*)(xp + 4);
            float v[8] = {v0.x, v0.y, v0.z, v0.w, v1.x, v1.y, v1.z, v1.w};
            short8 h8, l8;
#pragma unroll
            for (int j = 0; j < 8; ++j) {
                unsigned short hb, lb;
                split_bf(v[j], hb, lb);
                h8[j] = (short)hb; l8[j] = (short)lb;
            }
            ahi[r] = h8; alo[r] = l8;
        }
#pragma unroll
        for (int c = 0; c < 8; ++c) {
            size_t off = (size_t)(w * 128 + c * 16 + l15) * I_ + k0;
            short8 bhi = *(const short8*)(wih_hi + off);
            short8 blo = *(const short8*)(wih_lo + off);
#pragma unroll
            for (int r = 0; r < 2; ++r) {
                acc[r][c] = __builtin_amdgcn_mfma_f32_16x16x32_bf16(ahi[r], bhi, acc[r][c], 0, 0, 0);
                acc[r][c] = __builtin_amdgcn_mfma_f32_16x16x32_bf16(alo[r], bhi, acc[r][c], 0, 0, 0);
                acc[r][c] = __builtin_amdgcn_mfma_f32_16x16x32_bf16(ahi[r], blo, acc[r][c], 0, 0, 0);
            }
        }
    }

    // Per-row LN over the 128 cols of this gate chunk, then store to A.
#pragma unroll
    for (int r = 0; r < 2; ++r) {
        float s[4] = {0.f, 0.f, 0.f, 0.f}, ss[4] = {0.f, 0.f, 0.f, 0.f};
#pragma unroll
        for (int c = 0; c < 8; ++c)
#pragma unroll
            for (int i = 0; i < 4; ++i) {
                float v = acc[r][c][i];
                s[i] += v; ss[i] += v * v;
            }
#pragma unroll
        for (int m = 1; m < 16; m <<= 1)
#pragma unroll
            for (int i = 0; i < 4; ++i) {
                s[i]  += __shfl_xor(s[i],  m);
                ss[i] += __shfl_xor(ss[i], m);
            }
#pragma unroll
        for (int i = 0; i < 4; ++i) {
            float mu  = s[i] * (1.0f / 128.0f);
            float var = ss[i] * (1.0f / 128.0f) - mu * mu;
            float rs  = rsqrtf(var + EPS);
            size_t row = (size_t)(n0 + r * 16 + quad * 4 + i);
#pragma unroll
            for (int c = 0; c < 8; ++c) {
                float zn = (acc[r][c][i] - mu) * rs;
                A[row * G_ + w * 128 + c * 16 + l15] = zn * gx_c[c] + bs_c[c];
            }
        }
    }
}

// ---- persistent recurrence: each block runs its 32 batch rows through all T ----
__launch_bounds__(256, 2)
__global__ void recur_kernel(const float* __restrict__ A,                 // [B*T, G] fp32
                             const unsigned short* __restrict__ whh_hi,   // [G,H]
                             const unsigned short* __restrict__ whh_lo,   // [G,H]
                             const float* __restrict__ h0, const float* __restrict__ c0,
                             const float* __restrict__ gh,
                             const float* __restrict__ gc, const float* __restrict__ bc,
                             float* __restrict__ out) {
    __shared__ __align__(16) float gates[4 * 32 * 128];       // 64 KB
    __shared__ __align__(16) unsigned short hhi[32 * 128];    // 8 KB
    __shared__ __align__(16) unsigned short hlo[32 * 128];    // 8 KB

    const int tid  = threadIdx.x;
    const int w    = tid >> 6;
    const int lane = tid & 63;
    const int l15  = lane & 15;
    const int quad = lane >> 4;
    const int b0   = blockIdx.x * 32;

    float gh_c[8];
#pragma unroll
    for (int c = 0; c < 8; ++c) gh_c[c] = gh[w * 128 + c * 16 + l15];
    const float gcv0 = gc[lane], gcv1 = gc[lane + 64];
    const float bcv0 = bc[lane], bcv1 = bc[lane + 64];

    // h0 -> LDS (split bf16, swizzled)
#pragma unroll
    for (int j = 0; j < 16; ++j) {
        int e = j * 256 + tid;
        int row = e >> 7, col = e & 127;
        unsigned short hb, lb;
        split_bf(h0[(size_t)(b0 + row) * H_ + col], hb, lb);
        hhi[HIDX(row, col)] = hb;
        hlo[HIDX(row, col)] = lb;
    }
    // c0 -> registers (wave w owns rows w*8..w*8+7; cols lane, lane+64)
    float cr0[8], cr1[8];
#pragma unroll
    for (int rr = 0; rr < 8; ++rr) {
        size_t b = (size_t)(b0 + w * 8 + rr);
        cr0[rr] = c0[b * H_ + lane];
        cr1[rr] = c0[b * H_ + lane + 64];
    }

    // Prefetch A for t=0 into registers.
    const int arow = lane >> 5;       // 0 or 1
    const int c4   = lane & 31;       // float4 index within the 128-col chunk
    f32x4 a_pre[16];
#pragma unroll
    for (int j = 0; j < 16; ++j) {
        int row = j * 2 + arow;
        a_pre[j] = *(const f32x4*)(A + ((size_t)(b0 + row) * T_ + 0) * G_ + w * 128 + c4 * 4);
    }

    __syncthreads();

    for (int t = 0; t < T_; ++t) {
        // ---- deposit prefetched A_t into gates LDS (a_pre dies here,
        //      freeing its 64 VGPRs for phase B) ----
#pragma unroll
        for (int j = 0; j < 16; ++j) {
            int row = j * 2 + arow;
            *(f32x4*)&gates[GIDX(w, row, c4 * 4)] = a_pre[j];
        }

        // ---- phase B: h @ W_hh^T (K=128), split-bf16 3-term MFMA ----
        f32x4 acc[2][8];
#pragma unroll
        for (int r = 0; r < 2; ++r)
#pragma unroll
            for (int c = 0; c < 8; ++c) acc[r][c] = (f32x4){0.f, 0.f, 0.f, 0.f};

        for (int kk = 0; kk < 4; ++kk) {
            int k0 = kk * 32 + quad * 8;
            short8 ahi[2], alo[2];
#pragma unroll
            for (int r = 0; r < 2; ++r) {
                int lr = r * 16 + l15;
                int hx = HIDX(lr, k0);
                ahi[r] = *(const short8*)&hhi[hx];
                alo[r] = *(const short8*)&hlo[hx];
            }
#pragma unroll
            for (int c = 0; c < 8; ++c) {
                size_t off = (size_t)(w * 128 + c * 16 + l15) * H_ + k0;
                short8 bhi = *(const short8*)(whh_hi + off);
                short8 blo = *(const short8*)(whh_lo + off);
#pragma unroll
                for (int r = 0; r < 2; ++r) {
                    acc[r][c] = __builtin_amdgcn_mfma_f32_16x16x32_bf16(ahi[r], bhi, acc[r][c], 0, 0, 0);
                    acc[r][c] = __builtin_amdgcn_mfma_f32_16x16x32_bf16(alo[r], bhi, acc[r][c], 0, 0, 0);
                    acc[r][c] = __builtin_amdgcn_mfma_f32_16x16x32_bf16(ahi[r], blo, acc[r][c], 0, 0, 0);
                }
            }
        }

        // LN_h per row; accumulate hn*gh into gates (same lane wrote these addrs).
#pragma unroll
        for (int r = 0; r < 2; ++r) {
            float s[4] = {0.f, 0.f, 0.f, 0.f}, ss[4] = {0.f, 0.f, 0.f, 0.f};
#pragma unroll
            for (int c = 0; c < 8; ++c)
#pragma unroll
                for (int i = 0; i < 4; ++i) {
                    float v = acc[r][c][i];
                    s[i] += v; ss[i] += v * v;
                }
#pragma unroll
            for (int m = 1; m < 16; m <<= 1)
#pragma unroll
                for (int i = 0; i < 4; ++i) {
                    s[i]  += __shfl_xor(s[i],  m);
                    ss[i] += __shfl_xor(ss[i], m);
                }
#pragma unroll
            for (int i = 0; i < 4; ++i) {
                float mu  = s[i] * (1.0f / 128.0f);
                float var = ss[i] * (1.0f / 128.0f) - mu * mu;
                float rs  = rsqrtf(var + EPS);
                int row = r * 16 + quad * 4 + i;
#pragma unroll
                for (int c = 0; c < 8; ++c) {
                    float hn = (acc[r][c][i] - mu) * rs;
                    gates[GIDX(w, row, c * 16 + l15)] += hn * gh_c[c];
                }
            }
        }

        __syncthreads();

        // ---- prefetch A for t+1; completes under phase-2 math ----
        if (t + 1 < T_) {
#pragma unroll
            for (int j = 0; j < 16; ++j) {
                int row = j * 2 + arow;
                a_pre[j] = *(const f32x4*)(A + ((size_t)(b0 + row) * T_ + (t + 1)) * G_ + w * 128 + c4 * 4);
            }
        }

        // ---- phase 2: cell update + cell-LN + outputs; h stays in LDS ----
#pragma unroll
        for (int rr = 0; rr < 8; ++rr) {
            const int row = w * 8 + rr;
            const size_t b = (size_t)(b0 + row);
            float iv0 = gates[GIDX(0, row, lane)];
            float fv0 = gates[GIDX(1, row, lane)];
            float gv0 = gates[GIDX(2, row, lane)];
            float og0 = gates[GIDX(3, row, lane)];
            float iv1 = gates[GIDX(0, row, lane + 64)];
            float fv1 = gates[GIDX(1, row, lane + 64)];
            float gv1 = gates[GIDX(2, row, lane + 64)];
            float og1 = gates[GIDX(3, row, lane + 64)];

            float cn0 = sigm_(fv0) * cr0[rr] + sigm_(iv0) * tanh_(gv0);
            float cn1 = sigm_(fv1) * cr1[rr] + sigm_(iv1) * tanh_(gv1);
            float s = cn0 + cn1, ss = cn0 * cn0 + cn1 * cn1;
#pragma unroll
            for (int m = 1; m < 64; m <<= 1) {
                s  += __shfl_xor(s,  m);
                ss += __shfl_xor(ss, m);
            }
            float mu  = s * (1.0f / 128.0f);
            float var = ss * (1.0f / 128.0f) - mu * mu;
            float rs  = rsqrtf(var + EPS);

            float hv0 = sigm_(og0) * tanh_((cn0 - mu) * rs * gcv0 + bcv0);
            float hv1 = sigm_(og1) * tanh_((cn1 - mu) * rs * gcv1 + bcv1);
            cr0[rr] = cn0; cr1[rr] = cn1;

            unsigned short hb, lb;
            split_bf(hv0, hb, lb); hhi[HIDX(row, lane)]      = hb; hlo[HIDX(row, lane)]      = lb;
            split_bf(hv1, hb, lb); hhi[HIDX(row, lane + 64)] = hb; hlo[HIDX(row, lane + 64)] = lb;

            out[(b * T_ + t) * H_ + lane]      = hv0;
            out[(b * T_ + t) * H_ + lane + 64] = hv1;
            if (t == T_ - 1) {
                out[(size_t)B_ * T_ * H_ + b * H_ + lane]      = hv0;
                out[(size_t)B_ * T_ * H_ + b * H_ + lane + 64] = hv1;
            }
        }

        __syncthreads();   // h LDS + gates reuse barrier for next step
    }
}

extern "C" void kernel_launch(void* const* d_in, const int* in_sizes, int n_in,
                              void* d_out, int out_size, void* d_ws, size_t ws_size,
                              hipStream_t stream) {
    const float* x    = (const float*)d_in[0];
    const float* h0   = (const float*)d_in[1];
    const float* c0   = (const float*)d_in[2];
    const float* Wih  = (const float*)d_in[3];
    const float* Whh  = (const float*)d_in[4];
    const float* bias = (const float*)d_in[5];
    const float* gx   = (const float*)d_in[6];
    const float* bx   = (const float*)d_in[7];
    const float* gh   = (const float*)d_in[8];
    const float* bh   = (const float*)d_in[9];
    const float* gc   = (const float*)d_in[10];
    const float* bc   = (const float*)d_in[11];
    float* out = (float*)d_out;

    // ws layout (~513 MB of the 1 GiB workspace):
    //   A fp32 [B*T, G] | Wih hi/lo | Whh hi/lo
    char* ws = (char*)d_ws;
    size_t o = 0;
    float* A = (float*)(ws + o);                      o += (size_t)B_ * T_ * G_ * 4; // 512 MB
    unsigned short* wih_hi = (unsigned short*)(ws + o); o += (size_t)G_ * I_ * 2;    // 256 KB
    unsigned short* wih_lo = (unsigned short*)(ws + o); o += (size_t)G_ * I_ * 2;    // 256 KB
    unsigned short* whh_hi = (unsigned short*)(ws + o); o += (size_t)G_ * H_ * 2;    // 128 KB
    unsigned short* whh_lo = (unsigned short*)(ws + o);                              // 128 KB

    hipLaunchKernelGGL(prep_kernel, dim3(256), dim3(256), 0, stream,
                       Wih, Whh, wih_hi, wih_lo, whh_hi, whh_lo);

    hipLaunchKernelGGL(xproj_kernel, dim3(B_ * T_ / 32), dim3(256), 0, stream,
                       x, wih_hi, wih_lo, gx, bx, bh, bias, A);

    hipLaunchKernelGGL(recur_kernel, dim3(B_ / 32), dim3(256), 0, stream,
                       A, whh_hi, whh_lo, h0, c0, gh, gc, bc, out);
}

// Round 2
// 1835.212 us; speedup vs baseline: 1.0343x; 1.0180x over previous
//
#include <hip/hip_runtime.h>

// LayerNorm-LSTM: B=16384, T=16, I=256, H=128, G=4H=512.
// Round 4:
//  - recur: W_hh (hi+lo split-bf16) held in REGISTERS for the whole 16-step
//    loop (it is step-invariant). 8-wave blocks: each wave owns a 64-col
//    chunk -> B-fragments = exactly 128 VGPRs/lane. Eliminates the ~2 GB of
//    per-step whh re-fetches that made round 3 latency-bound (MfmaUtil 4.2%).
//    Per-gate LN now needs a 2-float/row partial exchange across wave pairs
//    (psum LDS + one extra barrier).
//  - nontemporal loads/stores for all streaming traffic (x, A, out) so the
//    weight panels stay L2-resident (the A/x streams were evicting them).
//  - A stored [T][B][G]: recur's per-step read = contiguous 64 KB/block.

#define B_  16384
#define T_  16
#define I_  256
#define H_  128
#define G_  512
#define EPS 1e-5f

typedef __attribute__((ext_vector_type(8))) short short8;   // 8 bf16 in 4 VGPRs
typedef __attribute__((ext_vector_type(4))) float f32x4;    // MFMA C/D frag
typedef __attribute__((ext_vector_type(2))) float f32x2;

__device__ __forceinline__ unsigned short f2bf(float f) {
    union { float f; unsigned u; } v; v.f = f;
    unsigned u = v.u;
    return (unsigned short)((u + 0x7FFFu + ((u >> 16) & 1u)) >> 16); // RNE
}
__device__ __forceinline__ float bf2f(unsigned short b) {
    union { unsigned u; float f; } v; v.u = ((unsigned)b) << 16;
    return v.f;
}
// split f32 -> hi (RTZ bf16) + lo (bf16 of exact residual)
__device__ __forceinline__ void split_bf(float x, unsigned short& hi, unsigned short& lo) {
    union { float f; unsigned u; } v; v.f = x;
    hi = (unsigned short)(v.u >> 16);
    lo = f2bf(x - bf2f(hi));
}

__device__ __forceinline__ float sigm_(float x) { return 1.0f / (1.0f + __expf(-x)); }
__device__ __forceinline__ float tanh_(float x) { return 1.0f - 2.0f / (__expf(2.0f * x) + 1.0f); }

__device__ __forceinline__ f32x4 ntload4(const float* p) {
    return __builtin_nontemporal_load((const f32x4*)p);
}

// LDS gate buffer index with quad-XOR swizzle (2-way bank aliasing max = free).
#define GIDX(g, row, col) ((((g) * 32 + (row)) * 128) + ((col) ^ (((row) & 12) << 2)))
// LDS h buffer index: XOR k-bits 3..5 by row so phase-B ds_read_b128 of the
// MFMA A-fragment is 2-way bank aliased (free).
#define HIDX(row, k) (((row) << 7) + ((k) ^ (((row) & 7) << 3)))

__global__ void prep_kernel(const float* __restrict__ Wih, const float* __restrict__ Whh,
                            unsigned short* __restrict__ wih_hi, unsigned short* __restrict__ wih_lo,
                            unsigned short* __restrict__ whh_hi, unsigned short* __restrict__ whh_lo) {
    const int NW_IH = G_ * I_;
    const int NW_HH = G_ * H_;
    int stride = gridDim.x * blockDim.x;
    for (int i = blockIdx.x * blockDim.x + threadIdx.x; i < NW_IH + NW_HH; i += stride) {
        unsigned short hi, lo;
        if (i < NW_IH) { split_bf(Wih[i], hi, lo); wih_hi[i] = hi; wih_lo[i] = lo; }
        else { int j = i - NW_IH; split_bf(Whh[j], hi, lo); whh_hi[j] = hi; whh_lo[j] = lo; }
    }
}

// ---- xproj: A[t][b][g] = LN_x(x_n @ Wih^T) * gx + (bx + bh + b), n = b*T+t ----
__launch_bounds__(256, 2)
__global__ void xproj_kernel(const float* __restrict__ x,                 // [B*T, I] fp32
                             const unsigned short* __restrict__ wih_hi,   // [G,I]
                             const unsigned short* __restrict__ wih_lo,   // [G,I]
                             const float* __restrict__ gx, const float* __restrict__ bx,
                             const float* __restrict__ bh, const float* __restrict__ bias,
                             float* __restrict__ A) {                     // [T, B, G] fp32
    const int tid  = threadIdx.x;
    const int w    = tid >> 6;     // wave id == gate chunk id
    const int lane = tid & 63;
    const int l15  = lane & 15;
    const int quad = lane >> 4;
    const int n0   = blockIdx.x * 32;

    float gx_c[8], bs_c[8];
#pragma unroll
    for (int c = 0; c < 8; ++c) {
        int col = w * 128 + c * 16 + l15;
        gx_c[c] = gx[col];
        bs_c[c] = bx[col] + bh[col] + bias[col];
    }

    f32x4 acc[2][8];
#pragma unroll
    for (int r = 0; r < 2; ++r)
#pragma unroll
        for (int c = 0; c < 8; ++c) acc[r][c] = (f32x4){0.f, 0.f, 0.f, 0.f};

    for (int kk = 0; kk < 8; ++kk) {
        int k0 = kk * 32 + quad * 8;
        short8 ahi[2], alo[2];
#pragma unroll
        for (int r = 0; r < 2; ++r) {
            const float* xp = x + (size_t)(n0 + r * 16 + l15) * I_ + k0;
            f32x4 v0 = ntload4(xp);
            f32x4 v1 = ntload4(xp + 4);
            float v[8] = {v0[0], v0[1], v0[2], v0[3], v1[0], v1[1], v1[2], v1[3]};
            short8 h8, l8;
#pragma unroll
            for (int j = 0; j < 8; ++j) {
                unsigned short hb, lb;
                split_bf(v[j], hb, lb);
                h8[j] = (short)hb; l8[j] = (short)lb;
            }
            ahi[r] = h8; alo[r] = l8;
        }
#pragma unroll
        for (int c = 0; c < 8; ++c) {
            size_t off = (size_t)(w * 128 + c * 16 + l15) * I_ + k0;
            short8 bhi = *(const short8*)(wih_hi + off);
            short8 blo = *(const short8*)(wih_lo + off);
#pragma unroll
            for (int r = 0; r < 2; ++r) {
                acc[r][c] = __builtin_amdgcn_mfma_f32_16x16x32_bf16(ahi[r], bhi, acc[r][c], 0, 0, 0);
                acc[r][c] = __builtin_amdgcn_mfma_f32_16x16x32_bf16(alo[r], bhi, acc[r][c], 0, 0, 0);
                acc[r][c] = __builtin_amdgcn_mfma_f32_16x16x32_bf16(ahi[r], blo, acc[r][c], 0, 0, 0);
            }
        }
    }

    // Per-row LN over the 128 cols of this gate chunk, store to A[t][b][g] (nt).
#pragma unroll
    for (int r = 0; r < 2; ++r) {
        float s[4] = {0.f, 0.f, 0.f, 0.f}, ss[4] = {0.f, 0.f, 0.f, 0.f};
#pragma unroll
        for (int c = 0; c < 8; ++c)
#pragma unroll
            for (int i = 0; i < 4; ++i) {
                float v = acc[r][c][i];
                s[i] += v; ss[i] += v * v;
            }
#pragma unroll
        for (int m = 1; m < 16; m <<= 1)
#pragma unroll
            for (int i = 0; i < 4; ++i) {
                s[i]  += __shfl_xor(s[i],  m);
                ss[i] += __shfl_xor(ss[i], m);
            }
#pragma unroll
        for (int i = 0; i < 4; ++i) {
            float mu  = s[i] * (1.0f / 128.0f);
            float var = ss[i] * (1.0f / 128.0f) - mu * mu;
            float rs  = rsqrtf(var + EPS);
            int n = n0 + r * 16 + quad * 4 + i;           // n = b*T + t
            size_t arow = (size_t)(n & (T_ - 1)) * B_ + (n >> 4);  // -> [t][b]
#pragma unroll
            for (int c = 0; c < 8; ++c) {
                float zn = (acc[r][c][i] - mu) * rs;
                __builtin_nontemporal_store(zn * gx_c[c] + bs_c[c],
                                            A + arow * G_ + w * 128 + c * 16 + l15);
            }
        }
    }
}

// ---- persistent recurrence: 512 threads (8 waves), 32 batch rows, all T steps,
//      W_hh held in registers ----
__launch_bounds__(512, 2)
__global__ void recur_kernel(const float* __restrict__ A,                 // [T, B, G] fp32
                             const unsigned short* __restrict__ whh_hi,   // [G,H]
                             const unsigned short* __restrict__ whh_lo,   // [G,H]
                             const float* __restrict__ h0, const float* __restrict__ c0,
                             const float* __restrict__ gh,
                             const float* __restrict__ gc, const float* __restrict__ bc,
                             float* __restrict__ out) {
    __shared__ __align__(16) float gates[4 * 32 * 128];       // 64 KB
    __shared__ __align__(16) unsigned short hhi[32 * 128];    // 8 KB
    __shared__ __align__(16) unsigned short hlo[32 * 128];    // 8 KB
    __shared__ __align__(16) f32x2 psum[8][32];               // 2 KB LN partials

    const int tid  = threadIdx.x;
    const int w    = tid >> 6;        // 0..7: wave owns cols w*64..w*64+63 of G
    const int lane = tid & 63;
    const int l15  = lane & 15;
    const int quad = lane >> 4;
    const int b0   = blockIdx.x * 32;
    const int gw    = w >> 1;         // gate of this wave
    const int cbase = (w & 1) * 64;   // col offset within gate

    float gh_c[4];
#pragma unroll
    for (int c = 0; c < 4; ++c) gh_c[c] = gh[w * 64 + c * 16 + l15];
    const float gcv0 = gc[lane], gcv1 = gc[lane + 64];
    const float bcv0 = bc[lane], bcv1 = bc[lane + 64];

    // ---- W_hh -> registers (hi/lo), t-invariant: 128 VGPRs/lane ----
    short8 wbh[4][4], wbl[4][4];      // [kk][c]
#pragma unroll
    for (int kk = 0; kk < 4; ++kk) {
        int k0 = kk * 32 + quad * 8;
#pragma unroll
        for (int c = 0; c < 4; ++c) {
            size_t off = (size_t)(w * 64 + c * 16 + l15) * H_ + k0;
            wbh[kk][c] = *(const short8*)(whh_hi + off);
            wbl[kk][c] = *(const short8*)(whh_lo + off);
        }
    }

    // h0 -> LDS (split bf16, swizzled)
#pragma unroll
    for (int j = 0; j < 8; ++j) {
        int e = j * 512 + tid;
        int row = e >> 7, col = e & 127;
        unsigned short hb, lb;
        split_bf(h0[(size_t)(b0 + row) * H_ + col], hb, lb);
        hhi[HIDX(row, col)] = hb;
        hlo[HIDX(row, col)] = lb;
    }
    // c0 -> registers (wave w owns rows w*4..w*4+3)
    float cr0[4], cr1[4];
#pragma unroll
    for (int rr = 0; rr < 4; ++rr) {
        size_t b = (size_t)(b0 + w * 4 + rr);
        cr0[rr] = c0[b * H_ + lane];
        cr1[rr] = c0[b * H_ + lane + 64];
    }

    // Prefetch A for t=0 (contiguous 64 KB per block in [T][B][G] layout).
    f32x4 a_pre[8];
#pragma unroll
    for (int j = 0; j < 8; ++j) {
        int e = j * 512 + tid;
        int row = e >> 7, col4 = e & 127;
        a_pre[j] = ntload4(A + ((size_t)b0 + row) * G_ + col4 * 4);
    }

    __syncthreads();

#pragma unroll 1
    for (int t = 0; t < T_; ++t) {
        // ---- deposit prefetched A_t into gates LDS ----
#pragma unroll
        for (int j = 0; j < 8; ++j) {
            int e = j * 512 + tid;
            int row = e >> 7, col4 = e & 127;
            int g = col4 >> 5, cig = (col4 & 31) * 4;
            *(f32x4*)&gates[GIDX(g, row, cig)] = a_pre[j];
        }

        // ---- phase B: h @ W_hh^T (K=128), whh from registers ----
        f32x4 acc[2][4];
#pragma unroll
        for (int r = 0; r < 2; ++r)
#pragma unroll
            for (int c = 0; c < 4; ++c) acc[r][c] = (f32x4){0.f, 0.f, 0.f, 0.f};

#pragma unroll
        for (int kk = 0; kk < 4; ++kk) {
            int k0 = kk * 32 + quad * 8;
            short8 ahi[2], alo[2];
#pragma unroll
            for (int r = 0; r < 2; ++r) {
                int hx = HIDX(r * 16 + l15, k0);
                ahi[r] = *(const short8*)&hhi[hx];
                alo[r] = *(const short8*)&hlo[hx];
            }
#pragma unroll
            for (int c = 0; c < 4; ++c)
#pragma unroll
                for (int r = 0; r < 2; ++r) {
                    acc[r][c] = __builtin_amdgcn_mfma_f32_16x16x32_bf16(ahi[r], wbh[kk][c], acc[r][c], 0, 0, 0);
                    acc[r][c] = __builtin_amdgcn_mfma_f32_16x16x32_bf16(alo[r], wbh[kk][c], acc[r][c], 0, 0, 0);
                    acc[r][c] = __builtin_amdgcn_mfma_f32_16x16x32_bf16(ahi[r], wbl[kk][c], acc[r][c], 0, 0, 0);
                }
        }

        // ---- LN_h partial sums over this wave's 64 cols ----
        float sA[2][4], ssA[2][4];
#pragma unroll
        for (int r = 0; r < 2; ++r) {
#pragma unroll
            for (int i = 0; i < 4; ++i) { sA[r][i] = 0.f; ssA[r][i] = 0.f; }
#pragma unroll
            for (int c = 0; c < 4; ++c)
#pragma unroll
                for (int i = 0; i < 4; ++i) {
                    float v = acc[r][c][i];
                    sA[r][i] += v; ssA[r][i] += v * v;
                }
#pragma unroll
            for (int m = 1; m < 16; m <<= 1)
#pragma unroll
                for (int i = 0; i < 4; ++i) {
                    sA[r][i]  += __shfl_xor(sA[r][i],  m);
                    ssA[r][i] += __shfl_xor(ssA[r][i], m);
                }
        }
        if (l15 == 0) {
#pragma unroll
            for (int r = 0; r < 2; ++r)
#pragma unroll
                for (int i = 0; i < 4; ++i) {
                    int row = r * 16 + quad * 4 + i;
                    psum[w][row] = (f32x2){sA[r][i], ssA[r][i]};
                }
        }

        __syncthreads();   // B1: deposits + psum partials visible

        // ---- finish LN with partner wave's partial; accumulate into gates ----
#pragma unroll
        for (int r = 0; r < 2; ++r)
#pragma unroll
            for (int i = 0; i < 4; ++i) {
                int row = r * 16 + quad * 4 + i;
                f32x2 p = psum[w ^ 1][row];
                float s  = sA[r][i] + p[0];
                float s2 = ssA[r][i] + p[1];
                float mu  = s * (1.0f / 128.0f);
                float var = s2 * (1.0f / 128.0f) - mu * mu;
                float rs  = rsqrtf(var + EPS);
#pragma unroll
                for (int c = 0; c < 4; ++c) {
                    float hn = (acc[r][c][i] - mu) * rs;
                    gates[GIDX(gw, row, cbase + c * 16 + l15)] += hn * gh_c[c];
                }
            }

        __syncthreads();   // B2: gates complete

        // ---- prefetch A for t+1; completes under phase-2 math ----
        if (t + 1 < T_) {
#pragma unroll
            for (int j = 0; j < 8; ++j) {
                int e = j * 512 + tid;
                int row = e >> 7, col4 = e & 127;
                a_pre[j] = ntload4(A + ((size_t)(t + 1) * B_ + b0 + row) * G_ + col4 * 4);
            }
        }

        // ---- phase 2: cell update + cell-LN + outputs (4 rows per wave) ----
#pragma unroll
        for (int rr = 0; rr < 4; ++rr) {
            const int row = w * 4 + rr;
            const size_t b = (size_t)(b0 + row);
            float iv0 = gates[GIDX(0, row, lane)];
            float fv0 = gates[GIDX(1, row, lane)];
            float gv0 = gates[GIDX(2, row, lane)];
            float og0 = gates[GIDX(3, row, lane)];
            float iv1 = gates[GIDX(0, row, lane + 64)];
            float fv1 = gates[GIDX(1, row, lane + 64)];
            float gv1 = gates[GIDX(2, row, lane + 64)];
            float og1 = gates[GIDX(3, row, lane + 64)];

            float cn0 = sigm_(fv0) * cr0[rr] + sigm_(iv0) * tanh_(gv0);
            float cn1 = sigm_(fv1) * cr1[rr] + sigm_(iv1) * tanh_(gv1);
            float s = cn0 + cn1, ss = cn0 * cn0 + cn1 * cn1;
#pragma unroll
            for (int m = 1; m < 64; m <<= 1) {
                s  += __shfl_xor(s,  m);
                ss += __shfl_xor(ss, m);
            }
            float mu  = s * (1.0f / 128.0f);
            float var = ss * (1.0f / 128.0f) - mu * mu;
            float rs  = rsqrtf(var + EPS);

            float hv0 = sigm_(og0) * tanh_((cn0 - mu) * rs * gcv0 + bcv0);
            float hv1 = sigm_(og1) * tanh_((cn1 - mu) * rs * gcv1 + bcv1);
            cr0[rr] = cn0; cr1[rr] = cn1;

            unsigned short hb, lb;
            split_bf(hv0, hb, lb); hhi[HIDX(row, lane)]      = hb; hlo[HIDX(row, lane)]      = lb;
            split_bf(hv1, hb, lb); hhi[HIDX(row, lane + 64)] = hb; hlo[HIDX(row, lane + 64)] = lb;

            __builtin_nontemporal_store(hv0, out + (b * T_ + t) * H_ + lane);
            __builtin_nontemporal_store(hv1, out + (b * T_ + t) * H_ + lane + 64);
            if (t == T_ - 1) {
                __builtin_nontemporal_store(hv0, out + (size_t)B_ * T_ * H_ + b * H_ + lane);
                __builtin_nontemporal_store(hv1, out + (size_t)B_ * T_ * H_ + b * H_ + lane + 64);
            }
        }

        __syncthreads();   // B3: h/gates reuse barrier for next step
    }
}

extern "C" void kernel_launch(void* const* d_in, const int* in_sizes, int n_in,
                              void* d_out, int out_size, void* d_ws, size_t ws_size,
                              hipStream_t stream) {
    const float* x    = (const float*)d_in[0];
    const float* h0   = (const float*)d_in[1];
    const float* c0   = (const float*)d_in[2];
    const float* Wih  = (const float*)d_in[3];
    const float* Whh  = (const float*)d_in[4];
    const float* bias = (const float*)d_in[5];
    const float* gx   = (const float*)d_in[6];
    const float* bx   = (const float*)d_in[7];
    const float* gh   = (const float*)d_in[8];
    const float* bh   = (const float*)d_in[9];
    const float* gc   = (const float*)d_in[10];
    const float* bc   = (const float*)d_in[11];
    float* out = (float*)d_out;

    // ws layout: A fp32 [T][B][G] (512 MB) | Wih hi/lo | Whh hi/lo
    char* ws = (char*)d_ws;
    size_t o = 0;
    float* A = (float*)(ws + o);                        o += (size_t)B_ * T_ * G_ * 4;
    unsigned short* wih_hi = (unsigned short*)(ws + o); o += (size_t)G_ * I_ * 2;
    unsigned short* wih_lo = (unsigned short*)(ws + o); o += (size_t)G_ * I_ * 2;
    unsigned short* whh_hi = (unsigned short*)(ws + o); o += (size_t)G_ * H_ * 2;
    unsigned short* whh_lo = (unsigned short*)(ws + o);

    hipLaunchKernelGGL(prep_kernel, dim3(256), dim3(256), 0, stream,
                       Wih, Whh, wih_hi, wih_lo, whh_hi, whh_lo);

    hipLaunchKernelGGL(xproj_kernel, dim3(B_ * T_ / 32), dim3(256), 0, stream,
                       x, wih_hi, wih_lo, gx, bx, bh, bias, A);

    hipLaunchKernelGGL(recur_kernel, dim3(B_ / 32), dim3(512), 0, stream,
                       A, whh_hi, whh_lo, h0, c0, gh, gc, bc, out);
}

// Round 3
// 1390.957 us; speedup vs baseline: 1.3647x; 1.3194x over previous
//
#include <hip/hip_runtime.h>

// LayerNorm-LSTM: B=16384, T=16, I=256, H=128, G=4H=512.
// Round 5:
//  - xproj: deep-ILP rebuild. All 16 weight fragments of a kk-step batched
//    into registers (16 independent L2 loads in flight) + x raw loads
//    double-buffered 2 kk ahead (~220 VGPR, launch_bounds(256,2)). Round-4's
//    104-VGPR version serialized the weight-load chain (MfmaUtil 10%).
//  - A stored PRE-SWIZZLED in recur's gates-linear layout ([T][1024 blk][8192]
//    floats, idx = (g*16+row)*128 + (col ^ ((row&12)<<2))) so recur's deposit
//    is a linear reg->LDS copy.
//  - recur: 16-row blocks (1024 blocks) -> LDS 41 KB -> 2 blocks/CU
//    co-resident (cross-block MFMA/VALU overlap). All in-loop barriers are
//    raw "s_waitcnt lgkmcnt(0); s_barrier" so the A(t+1) register prefetch
//    (issued at step top) stays in flight across the whole step; the only
//    vmcnt wait is the compiler-inserted one at the deposit.
//  - W_hh stays in registers (128 VGPR, t-invariant). setprio(1) around MFMAs.

#define B_  16384
#define T_  16
#define I_  256
#define H_  128
#define G_  512
#define EPS 1e-5f

typedef __attribute__((ext_vector_type(8))) short short8;   // 8 bf16 in 4 VGPRs
typedef __attribute__((ext_vector_type(4))) float f32x4;    // MFMA C/D frag
typedef __attribute__((ext_vector_type(2))) float f32x2;

__device__ __forceinline__ unsigned short f2bf(float f) {
    union { float f; unsigned u; } v; v.f = f;
    unsigned u = v.u;
    return (unsigned short)((u + 0x7FFFu + ((u >> 16) & 1u)) >> 16); // RNE
}
__device__ __forceinline__ float bf2f(unsigned short b) {
    union { unsigned u; float f; } v; v.u = ((unsigned)b) << 16;
    return v.f;
}
// split f32 -> hi (RTZ bf16) + lo (bf16 of exact residual)
__device__ __forceinline__ void split_bf(float x, unsigned short& hi, unsigned short& lo) {
    union { float f; unsigned u; } v; v.f = x;
    hi = (unsigned short)(v.u >> 16);
    lo = f2bf(x - bf2f(hi));
}

__device__ __forceinline__ float sigm_(float x) { return 1.0f / (1.0f + __expf(-x)); }
__device__ __forceinline__ float tanh_(float x) { return 1.0f - 2.0f / (__expf(2.0f * x) + 1.0f); }

__device__ __forceinline__ f32x4 ntload4(const float* p) {
    return __builtin_nontemporal_load((const f32x4*)p);
}
// raw workgroup barrier: drain LDS ops only, leave global loads in flight
__device__ __forceinline__ void bar_lgkm() {
    asm volatile("s_waitcnt lgkmcnt(0)\n\ts_barrier" ::: "memory");
}

// gates LDS index (16-row blocks) with quad-XOR swizzle (bank-conflict-free
// RMW across quads; 2-way aliasing elsewhere = free).
#define GIDX16(g, row, col) ((((g) * 16 + (row)) * 128) + ((col) ^ (((row) & 12) << 2)))
// LDS h buffer index: XOR k-bits 3..5 by row so phase-B ds_read_b128 of the
// MFMA A-fragment is 2-way bank aliased (free).
#define HIDX(row, k) (((row) << 7) + ((k) ^ (((row) & 7) << 3)))

__global__ void prep_kernel(const float* __restrict__ Wih, const float* __restrict__ Whh,
                            unsigned short* __restrict__ wih_hi, unsigned short* __restrict__ wih_lo,
                            unsigned short* __restrict__ whh_hi, unsigned short* __restrict__ whh_lo) {
    const int NW_IH = G_ * I_;
    const int NW_HH = G_ * H_;
    int stride = gridDim.x * blockDim.x;
    for (int i = blockIdx.x * blockDim.x + threadIdx.x; i < NW_IH + NW_HH; i += stride) {
        unsigned short hi, lo;
        if (i < NW_IH) { split_bf(Wih[i], hi, lo); wih_hi[i] = hi; wih_lo[i] = lo; }
        else { int j = i - NW_IH; split_bf(Whh[j], hi, lo); whh_hi[j] = hi; whh_lo[j] = lo; }
    }
}

// ---- xproj: A = LN_x(x @ Wih^T) * gx + (bx + bh + b), stored pre-swizzled
//      per recur block: A[((t*1024+blk)*8192) + GIDX16-linear] ----
__launch_bounds__(256, 2)
__global__ void xproj_kernel(const float* __restrict__ x,                 // [B*T, I] fp32
                             const unsigned short* __restrict__ wih_hi,   // [G,I]
                             const unsigned short* __restrict__ wih_lo,   // [G,I]
                             const float* __restrict__ gx, const float* __restrict__ bx,
                             const float* __restrict__ bh, const float* __restrict__ bias,
                             float* __restrict__ A) {
    const int tid  = threadIdx.x;
    const int w    = tid >> 6;     // wave id == gate chunk id
    const int lane = tid & 63;
    const int l15  = lane & 15;
    const int quad = lane >> 4;
    const int n0   = blockIdx.x * 32;

    float gx_c[8], bs_c[8];
#pragma unroll
    for (int c = 0; c < 8; ++c) {
        int col = w * 128 + c * 16 + l15;
        gx_c[c] = gx[col];
        bs_c[c] = bx[col] + bh[col] + bias[col];
    }

    f32x4 acc[2][8];
#pragma unroll
    for (int r = 0; r < 2; ++r)
#pragma unroll
        for (int c = 0; c < 8; ++c) acc[r][c] = (f32x4){0.f, 0.f, 0.f, 0.f};

    // x double-buffer, 2 kk-steps deep
    f32x4 xb[2][2][2];   // [parity][r][half]
#pragma unroll
    for (int p = 0; p < 2; ++p)
#pragma unroll
        for (int r = 0; r < 2; ++r) {
            const float* xp = x + (size_t)(n0 + r * 16 + l15) * I_ + p * 32 + quad * 8;
            xb[p][r][0] = ntload4(xp);
            xb[p][r][1] = ntload4(xp + 4);
        }

#pragma unroll
    for (int kk = 0; kk < 8; ++kk) {
        const int k0 = kk * 32 + quad * 8;
        // batch all 16 weight fragments (independent L2 loads in flight)
        short8 wh8[8], wl8[8];
#pragma unroll
        for (int c = 0; c < 8; ++c) {
            size_t off = (size_t)(w * 128 + c * 16 + l15) * I_ + k0;
            wh8[c] = *(const short8*)(wih_hi + off);
            wl8[c] = *(const short8*)(wih_lo + off);
        }
        // split current x buffer (VALU; overlaps weight-load latency)
        short8 ahi[2], alo[2];
#pragma unroll
        for (int r = 0; r < 2; ++r) {
            float v[8] = {xb[kk & 1][r][0][0], xb[kk & 1][r][0][1],
                          xb[kk & 1][r][0][2], xb[kk & 1][r][0][3],
                          xb[kk & 1][r][1][0], xb[kk & 1][r][1][1],
                          xb[kk & 1][r][1][2], xb[kk & 1][r][1][3]};
            short8 h8, l8;
#pragma unroll
            for (int j = 0; j < 8; ++j) {
                unsigned short hb, lb;
                split_bf(v[j], hb, lb);
                h8[j] = (short)hb; l8[j] = (short)lb;
            }
            ahi[r] = h8; alo[r] = l8;
        }
        // refill this parity with kk+2's x (consumed 2 iterations from now)
        if (kk + 2 < 8) {
#pragma unroll
            for (int r = 0; r < 2; ++r) {
                const float* xp = x + (size_t)(n0 + r * 16 + l15) * I_ + (kk + 2) * 32 + quad * 8;
                xb[kk & 1][r][0] = ntload4(xp);
                xb[kk & 1][r][1] = ntload4(xp + 4);
            }
        }
#pragma unroll
        for (int c = 0; c < 8; ++c)
#pragma unroll
            for (int r = 0; r < 2; ++r) {
                acc[r][c] = __builtin_amdgcn_mfma_f32_16x16x32_bf16(ahi[r], wh8[c], acc[r][c], 0, 0, 0);
                acc[r][c] = __builtin_amdgcn_mfma_f32_16x16x32_bf16(alo[r], wh8[c], acc[r][c], 0, 0, 0);
                acc[r][c] = __builtin_amdgcn_mfma_f32_16x16x32_bf16(ahi[r], wl8[c], acc[r][c], 0, 0, 0);
            }
    }

    // Per-row LN over the 128 cols of this gate chunk; store pre-swizzled.
#pragma unroll
    for (int r = 0; r < 2; ++r) {
        float s[4] = {0.f, 0.f, 0.f, 0.f}, ss[4] = {0.f, 0.f, 0.f, 0.f};
#pragma unroll
        for (int c = 0; c < 8; ++c)
#pragma unroll
            for (int i = 0; i < 4; ++i) {
                float v = acc[r][c][i];
                s[i] += v; ss[i] += v * v;
            }
#pragma unroll
        for (int m = 1; m < 16; m <<= 1)
#pragma unroll
            for (int i = 0; i < 4; ++i) {
                s[i]  += __shfl_xor(s[i],  m);
                ss[i] += __shfl_xor(ss[i], m);
            }
#pragma unroll
        for (int i = 0; i < 4; ++i) {
            float mu  = s[i] * (1.0f / 128.0f);
            float var = ss[i] * (1.0f / 128.0f) - mu * mu;
            float rs  = rsqrtf(var + EPS);
            int n = n0 + r * 16 + quad * 4 + i;   // n = b*T + t
            int b = n >> 4, t = n & 15;
            size_t base = ((size_t)t * 1024 + (b >> 4)) * 8192 + (size_t)(w * 16 + (b & 15)) * 128;
            int swz = ((b & 15) & 12) << 2;
#pragma unroll
            for (int c = 0; c < 8; ++c) {
                float zn = (acc[r][c][i] - mu) * rs;
                __builtin_nontemporal_store(zn * gx_c[c] + bs_c[c],
                                            A + base + ((c * 16 + l15) ^ swz));
            }
        }
    }
}

// ---- persistent recurrence: 1024 blocks x 16 rows, 512 threads (8 waves),
//      W_hh in registers, all T steps ----
__launch_bounds__(512, 2)
__global__ void recur_kernel(const float* __restrict__ A,                 // [T][1024][8192]
                             const unsigned short* __restrict__ whh_hi,   // [G,H]
                             const unsigned short* __restrict__ whh_lo,   // [G,H]
                             const float* __restrict__ h0, const float* __restrict__ c0,
                             const float* __restrict__ gh,
                             const float* __restrict__ gc, const float* __restrict__ bc,
                             float* __restrict__ out) {
    __shared__ __align__(16) float gates[4 * 16 * 128];       // 32 KB
    __shared__ __align__(16) unsigned short hhi[16 * 128];    // 4 KB
    __shared__ __align__(16) unsigned short hlo[16 * 128];    // 4 KB
    __shared__ __align__(16) f32x2 psum[8][16];               // 1 KB

    const int tid  = threadIdx.x;
    const int w    = tid >> 6;        // 0..7: wave owns G-cols w*64..w*64+63
    const int lane = tid & 63;
    const int l15  = lane & 15;
    const int quad = lane >> 4;
    const int b0   = blockIdx.x * 16;
    const int gw    = w >> 1;         // gate of this wave
    const int cbase = (w & 1) * 64;   // col offset within gate

    float gh_c[4];
#pragma unroll
    for (int c = 0; c < 4; ++c) gh_c[c] = gh[w * 64 + c * 16 + l15];
    const float gcv0 = gc[lane], gcv1 = gc[lane + 64];
    const float bcv0 = bc[lane], bcv1 = bc[lane + 64];

    // ---- W_hh -> registers (hi/lo), t-invariant: 128 VGPRs/lane ----
    short8 wbh[4][4], wbl[4][4];      // [kk][c]
#pragma unroll
    for (int kk = 0; kk < 4; ++kk) {
        int k0 = kk * 32 + quad * 8;
#pragma unroll
        for (int c = 0; c < 4; ++c) {
            size_t off = (size_t)(w * 64 + c * 16 + l15) * H_ + k0;
            wbh[kk][c] = *(const short8*)(whh_hi + off);
            wbl[kk][c] = *(const short8*)(whh_lo + off);
        }
    }

    // h0 -> LDS (split bf16, swizzled): 2048 elems, 4 per thread
#pragma unroll
    for (int j = 0; j < 4; ++j) {
        int e = j * 512 + tid;
        int row = e >> 7, col = e & 127;
        unsigned short hb, lb;
        split_bf(h0[(size_t)(b0 + row) * H_ + col], hb, lb);
        hhi[HIDX(row, col)] = hb;
        hlo[HIDX(row, col)] = lb;
    }
    // c0 -> registers (wave w owns rows w*2..w*2+1)
    float cr0[2], cr1[2];
#pragma unroll
    for (int rr = 0; rr < 2; ++rr) {
        size_t b = (size_t)(b0 + w * 2 + rr);
        cr0[rr] = c0[b * H_ + lane];
        cr1[rr] = c0[b * H_ + lane + 64];
    }

    // Prefetch A for t=0 (32 KB/block, gates-linear layout).
    f32x4 a_pre[4];
#pragma unroll
    for (int j = 0; j < 4; ++j)
        a_pre[j] = ntload4(A + (size_t)blockIdx.x * 8192 + (size_t)(j * 512 + tid) * 4);

    __syncthreads();   // prologue only: h0 LDS visible

#pragma unroll 1
    for (int t = 0; t < T_; ++t) {
        // ---- deposit A_t into gates (linear; compiler waits vmcnt here) ----
#pragma unroll
        for (int j = 0; j < 4; ++j)
            *(f32x4*)&gates[(j * 512 + tid) * 4] = a_pre[j];

        // ---- issue A(t+1) prefetch: a full step to land ----
        if (t + 1 < T_) {
#pragma unroll
            for (int j = 0; j < 4; ++j)
                a_pre[j] = ntload4(A + ((size_t)(t + 1) * 1024 + blockIdx.x) * 8192
                                     + (size_t)(j * 512 + tid) * 4);
        }

        // ---- phase B: h @ W_hh^T (K=128), whh from registers ----
        f32x4 acc[4];
#pragma unroll
        for (int c = 0; c < 4; ++c) acc[c] = (f32x4){0.f, 0.f, 0.f, 0.f};

        __builtin_amdgcn_s_setprio(1);
#pragma unroll
        for (int kk = 0; kk < 4; ++kk) {
            int k0 = kk * 32 + quad * 8;
            int hx = HIDX(l15, k0);
            short8 ahi = *(const short8*)&hhi[hx];
            short8 alo = *(const short8*)&hlo[hx];
#pragma unroll
            for (int c = 0; c < 4; ++c) {
                acc[c] = __builtin_amdgcn_mfma_f32_16x16x32_bf16(ahi, wbh[kk][c], acc[c], 0, 0, 0);
                acc[c] = __builtin_amdgcn_mfma_f32_16x16x32_bf16(alo, wbh[kk][c], acc[c], 0, 0, 0);
                acc[c] = __builtin_amdgcn_mfma_f32_16x16x32_bf16(ahi, wbl[kk][c], acc[c], 0, 0, 0);
            }
        }
        __builtin_amdgcn_s_setprio(0);

        // ---- LN_h partial sums over this wave's 64 cols ----
        float sA[4], ssA[4];
#pragma unroll
        for (int i = 0; i < 4; ++i) { sA[i] = 0.f; ssA[i] = 0.f; }
#pragma unroll
        for (int c = 0; c < 4; ++c)
#pragma unroll
            for (int i = 0; i < 4; ++i) {
                float v = acc[c][i];
                sA[i] += v; ssA[i] += v * v;
            }
#pragma unroll
        for (int m = 1; m < 16; m <<= 1)
#pragma unroll
            for (int i = 0; i < 4; ++i) {
                sA[i]  += __shfl_xor(sA[i],  m);
                ssA[i] += __shfl_xor(ssA[i], m);
            }
        if (l15 == 0) {
#pragma unroll
            for (int i = 0; i < 4; ++i)
                psum[w][quad * 4 + i] = (f32x2){sA[i], ssA[i]};
        }

        bar_lgkm();   // B1: deposits + psum visible (A(t+1) loads stay in flight)

        // ---- finish LN with partner wave's partial; accumulate into gates ----
#pragma unroll
        for (int i = 0; i < 4; ++i) {
            int row = quad * 4 + i;
            f32x2 p = psum[w ^ 1][row];
            float s  = sA[i] + p[0];
            float s2 = ssA[i] + p[1];
            float mu  = s * (1.0f / 128.0f);
            float var = s2 * (1.0f / 128.0f) - mu * mu;
            float rs  = rsqrtf(var + EPS);
#pragma unroll
            for (int c = 0; c < 4; ++c) {
                float hn = (acc[c][i] - mu) * rs;
                gates[GIDX16(gw, row, cbase + c * 16 + l15)] += hn * gh_c[c];
            }
        }

        bar_lgkm();   // B2: gates complete

        // ---- phase 2: cell update + cell-LN + outputs (2 rows per wave) ----
#pragma unroll
        for (int rr = 0; rr < 2; ++rr) {
            const int row = w * 2 + rr;
            const size_t b = (size_t)(b0 + row);
            float iv0 = gates[GIDX16(0, row, lane)];
            float fv0 = gates[GIDX16(1, row, lane)];
            float gv0 = gates[GIDX16(2, row, lane)];
            float og0 = gates[GIDX16(3, row, lane)];
            float iv1 = gates[GIDX16(0, row, lane + 64)];
            float fv1 = gates[GIDX16(1, row, lane + 64)];
            float gv1 = gates[GIDX16(2, row, lane + 64)];
            float og1 = gates[GIDX16(3, row, lane + 64)];

            float cn0 = sigm_(fv0) * cr0[rr] + sigm_(iv0) * tanh_(gv0);
            float cn1 = sigm_(fv1) * cr1[rr] + sigm_(iv1) * tanh_(gv1);
            float s = cn0 + cn1, ss = cn0 * cn0 + cn1 * cn1;
#pragma unroll
            for (int m = 1; m < 64; m <<= 1) {
                s  += __shfl_xor(s,  m);
                ss += __shfl_xor(ss, m);
            }
            float mu  = s * (1.0f / 128.0f);
            float var = ss * (1.0f / 128.0f) - mu * mu;
            float rs  = rsqrtf(var + EPS);

            float hv0 = sigm_(og0) * tanh_((cn0 - mu) * rs * gcv0 + bcv0);
            float hv1 = sigm_(og1) * tanh_((cn1 - mu) * rs * gcv1 + bcv1);
            cr0[rr] = cn0; cr1[rr] = cn1;

            unsigned short hb, lb;
            split_bf(hv0, hb, lb); hhi[HIDX(row, lane)]      = hb; hlo[HIDX(row, lane)]      = lb;
            split_bf(hv1, hb, lb); hhi[HIDX(row, lane + 64)] = hb; hlo[HIDX(row, lane + 64)] = lb;

            __builtin_nontemporal_store(hv0, out + (b * T_ + t) * H_ + lane);
            __builtin_nontemporal_store(hv1, out + (b * T_ + t) * H_ + lane + 64);
            if (t == T_ - 1) {
                __builtin_nontemporal_store(hv0, out + (size_t)B_ * T_ * H_ + b * H_ + lane);
                __builtin_nontemporal_store(hv1, out + (size_t)B_ * T_ * H_ + b * H_ + lane + 64);
            }
        }

        bar_lgkm();   // B3: h/gates reuse barrier for next step
    }
}

extern "C" void kernel_launch(void* const* d_in, const int* in_sizes, int n_in,
                              void* d_out, int out_size, void* d_ws, size_t ws_size,
                              hipStream_t stream) {
    const float* x    = (const float*)d_in[0];
    const float* h0   = (const float*)d_in[1];
    const float* c0   = (const float*)d_in[2];
    const float* Wih  = (const float*)d_in[3];
    const float* Whh  = (const float*)d_in[4];
    const float* bias = (const float*)d_in[5];
    const float* gx   = (const float*)d_in[6];
    const float* bx   = (const float*)d_in[7];
    const float* gh   = (const float*)d_in[8];
    const float* bh   = (const float*)d_in[9];
    const float* gc   = (const float*)d_in[10];
    const float* bc   = (const float*)d_in[11];
    float* out = (float*)d_out;

    // ws layout: A fp32 [T][1024][8192] (512 MB, pre-swizzled) | Wih hi/lo | Whh hi/lo
    char* ws = (char*)d_ws;
    size_t o = 0;
    float* A = (float*)(ws + o);                        o += (size_t)B_ * T_ * G_ * 4;
    unsigned short* wih_hi = (unsigned short*)(ws + o); o += (size_t)G_ * I_ * 2;
    unsigned short* wih_lo = (unsigned short*)(ws + o); o += (size_t)G_ * I_ * 2;
    unsigned short* whh_hi = (unsigned short*)(ws + o); o += (size_t)G_ * H_ * 2;
    unsigned short* whh_lo = (unsigned short*)(ws + o);

    hipLaunchKernelGGL(prep_kernel, dim3(256), dim3(256), 0, stream,
                       Wih, Whh, wih_hi, wih_lo, whh_hi, whh_lo);

    hipLaunchKernelGGL(xproj_kernel, dim3(B_ * T_ / 32), dim3(256), 0, stream,
                       x, wih_hi, wih_lo, gx, bx, bh, bias, A);

    hipLaunchKernelGGL(recur_kernel, dim3(B_ / 16), dim3(512), 0, stream,
                       A, whh_hi, whh_lo, h0, c0, gh, gc, bc, out);
}